// Round 12
// baseline (126.532 us; speedup 1.0000x reference)
//
#include <hip/hip_runtime.h>
#include <math.h>

// LinearAttentionBlock — bf16 MFMA v11 == r9 (proven best, 122.5us).
// B=16, N=8192, D=128, H=4, dh=32, FF=512. mfma_f32_16x16x32_bf16.
// kw: weights -> bf16 [n][k].
// k1: staged-weight pipeline (single 16KB wbuf, reg-staged one segment ahead).
// k2: reduce partials -> KVt bf16 [m][d], Ksum f32.
// k3: 21-segment reg-staged weight pipeline (double-buffered 16KB half-panels,
//     chunk-swizzled), identity-MFMA residuals, native cvt_pk bf16, setprio.

using bfrag = __attribute__((ext_vector_type(8))) short;   // 8 bf16 (MFMA A/B)
using sh4   = __attribute__((ext_vector_type(4))) short;   // 4 bf16
using ffrag = __attribute__((ext_vector_type(4))) float;   // MFMA C/D

#define MFMA(a, b, c) __builtin_amdgcn_mfma_f32_16x16x32_bf16((a), (b), (c), 0, 0, 0)

__device__ __forceinline__ float phi_fn(float v) { return v > 0.f ? v + 1.f : __expf(v); }

// native bf16 convert (RNE) — compiler emits v_cvt_pk_bf16_f32 for pairs
__device__ __forceinline__ short f2bf(float f) {
    __bf16 h = (__bf16)f;
    return *(short*)&h;
}
__device__ __forceinline__ float bf2f(short s) {
    union { unsigned u; float f; } v; v.u = ((unsigned)(unsigned short)s) << 16;
    return v.f;
}

// ---------------- kw: weight convert + transpose ----------------
__global__ void kw_conv(const float* __restrict__ Wq, const float* __restrict__ Wk,
                        const float* __restrict__ Wv, const float* __restrict__ Wo,
                        const float* __restrict__ W1, const float* __restrict__ W2,
                        short* __restrict__ Wqt, short* __restrict__ Wkt,
                        short* __restrict__ Wvt, short* __restrict__ Wot,
                        short* __restrict__ W1t, short* __restrict__ W2t) {
    int i = blockIdx.x * 256 + threadIdx.x;
    if (i < 65536) {
        int mat = i >> 14, q = i & 16383, n = q >> 7, k = q & 127;
        const float* S = mat == 0 ? Wq : mat == 1 ? Wk : mat == 2 ? Wv : Wo;
        short* D = mat == 0 ? Wqt : mat == 1 ? Wkt : mat == 2 ? Wvt : Wot;
        D[n * 128 + k] = f2bf(S[k * 128 + n]);
    } else if (i < 131072) {
        int q = i - 65536, n = q >> 7, k = q & 127;
        W1t[n * 128 + k] = f2bf(W1[k * 512 + n]);
    } else {
        int q = i - 131072, n = q >> 9, k = q & 511;
        W2t[n * 512 + k] = f2bf(W2[k * 128 + n]);
    }
}

// ---------------- k1 v2: K/V proj + partial KV, staged-weight pipeline ----------------
__global__ __launch_bounds__(256, 2) void k1_kv(
    const float* __restrict__ x, const short* __restrict__ Wkt,
    const short* __restrict__ Wvt, short* __restrict__ partKV,
    float* __restrict__ partKs) {
    __shared__ short sx[64][136];   // 17.4KB
    __shared__ short Kt[128][72];   // 18.4KB [dim][token]
    __shared__ short Vt[128][72];   // 18.4KB
    __shared__ short wbuf[8192];    // 16KB: one 64x128 half-panel, chunk-swizzled

    const int t = threadIdx.x, w = t >> 6, l = t & 63, lr = l & 15, lg = l >> 4;
    const int blk = blockIdx.x, b = blk >> 5;
    const size_t tok0 = ((size_t)b << 13) + (size_t)(blk & 31) * 256;
    const ffrag fz = {0.f, 0.f, 0.f, 0.f};

    const int srow0 = w * 4 + (l >> 4);  // 0..15; rows srow0+{0,16,32,48}
    const int scol = lr;
    const int cl = scol ^ srow0;
    int4 sg0, sg1, sg2, sg3;
    auto stage_load = [&](const short* src) {
        sg0 = *(const int4*)(src + (srow0 +  0) * 128 + scol * 8);
        sg1 = *(const int4*)(src + (srow0 + 16) * 128 + scol * 8);
        sg2 = *(const int4*)(src + (srow0 + 32) * 128 + scol * 8);
        sg3 = *(const int4*)(src + (srow0 + 48) * 128 + scol * 8);
    };
    auto stage_write = [&]() {
        *(int4*)(wbuf + (srow0 +  0) * 128 + cl * 8) = sg0;
        *(int4*)(wbuf + (srow0 + 16) * 128 + cl * 8) = sg1;
        *(int4*)(wbuf + (srow0 + 32) * 128 + cl * 8) = sg2;
        *(int4*)(wbuf + (srow0 + 48) * 128 + cl * 8) = sg3;
    };
    auto wfrag = [&](int q, int kk) -> bfrag {
        return *(const bfrag*)(wbuf + (q * 16 + lr) * 128 + (((kk * 4 + lg) ^ lr) * 8));
    };

    ffrag kvacc[2][2];
#pragma unroll
    for (int dt = 0; dt < 2; dt++)
#pragma unroll
        for (int mt = 0; mt < 2; mt++) kvacc[dt][mt] = fz;
    float accKs[8];
#pragma unroll
    for (int i = 0; i < 8; i++) accKs[i] = 0.f;

    stage_load(Wkt);  // panel 0 = Wk h0

    for (int s = 0; s < 4; ++s) {
        const float* xb = x + (tok0 + (size_t)s * 64 + w * 16) * 128;
#pragma unroll
        for (int it = 0; it < 4; ++it) {
            int idx = it * 64 + l, row = idx >> 4, c8 = (idx & 15) * 8;
            const float4* p = (const float4*)(xb + row * 128 + c8);
            float4 v0 = p[0], v1 = p[1];
            bfrag sv;
            sv[0] = f2bf(v0.x); sv[1] = f2bf(v0.y); sv[2] = f2bf(v0.z); sv[3] = f2bf(v0.w);
            sv[4] = f2bf(v1.x); sv[5] = f2bf(v1.y); sv[6] = f2bf(v1.z); sv[7] = f2bf(v1.w);
            *(bfrag*)&sx[w * 16 + row][c8] = sv;
        }
        bfrag xf[4];
#pragma unroll
        for (int kk = 0; kk < 4; kk++)
            xf[kk] = *(const bfrag*)&sx[w * 16 + lr][kk * 32 + lg * 8];
        const int toff = w * 16 + lg * 4;

        // 4 weight segments: p = 0:Wk h0, 1:Wk h1, 2:Wv h0, 3:Wv h1
#pragma unroll
        for (int p = 0; p < 4; ++p) {
            __syncthreads();   // prior wbuf readers done
            stage_write();
            int nseg = s * 4 + p + 1;
            if (nseg < 16) {
                const short* nsrc = ((nseg & 2) ? Wvt : Wkt) + ((nseg & 1) ? 8192 : 0);
                stage_load(nsrc);
            }
            __syncthreads();   // wbuf ready
            const int half = p & 1;
#pragma unroll
            for (int q = 0; q < 4; q++) {
                const int n0 = half * 4 + q;
                ffrag c = fz;
#pragma unroll
                for (int kk = 0; kk < 4; kk++) c = MFMA(xf[kk], wfrag(q, kk), c);
                if (p < 2) {  // K: phi + Ksum + Kt
                    sh4 ks;
#pragma unroll
                    for (int j = 0; j < 4; j++) {
                        float pv = phi_fn(c[j]);
                        accKs[n0] += pv;
                        ks[j] = f2bf(pv);
                    }
                    *(sh4*)&Kt[n0 * 16 + lr][toff] = ks;
                } else {      // V
                    sh4 vs;
#pragma unroll
                    for (int j = 0; j < 4; j++) vs[j] = f2bf(c[j]);
                    *(sh4*)&Vt[n0 * 16 + lr][toff] = vs;
                }
            }
        }
        __syncthreads();  // Kt/Vt complete for this subtile

#pragma unroll
        for (int kk = 0; kk < 2; kk++) {
            bfrag ka0 = *(const bfrag*)&Kt[w * 32 + lr][kk * 32 + lg * 8];
            bfrag ka1 = *(const bfrag*)&Kt[w * 32 + 16 + lr][kk * 32 + lg * 8];
            bfrag vb0 = *(const bfrag*)&Vt[w * 32 + lr][kk * 32 + lg * 8];
            bfrag vb1 = *(const bfrag*)&Vt[w * 32 + 16 + lr][kk * 32 + lg * 8];
            kvacc[0][0] = MFMA(ka0, vb0, kvacc[0][0]);
            kvacc[0][1] = MFMA(ka0, vb1, kvacc[0][1]);
            kvacc[1][0] = MFMA(ka1, vb0, kvacc[1][0]);
            kvacc[1][1] = MFMA(ka1, vb1, kvacc[1][1]);
        }
    }
    short* pk = partKV + ((size_t)(blk * 4 + w) << 10);
#pragma unroll
    for (int dt = 0; dt < 2; dt++)
#pragma unroll
        for (int mt = 0; mt < 2; mt++)
#pragma unroll
            for (int j = 0; j < 4; j++)
                pk[(dt * 16 + lg * 4 + j) * 32 + mt * 16 + lr] = f2bf(kvacc[dt][mt][j]);
#pragma unroll
    for (int n0 = 0; n0 < 8; n0++) {
        float v = accKs[n0];
        v += __shfl_xor(v, 16);
        v += __shfl_xor(v, 32);
        if (l < 16) partKs[(blk * 4 + w) * 128 + n0 * 16 + l] = v;
    }
}

// ---------------- k2: reduce partials ----------------
__global__ void k2_red(const short* __restrict__ partKV, const float* __restrict__ partKs,
                       short* __restrict__ KVt, float* __restrict__ Ksf) {
    int bh = blockIdx.x, b = bh >> 2, h = bh & 3, t = threadIdx.x;
    for (int idx = t; idx < 1024; idx += 256) {
        int d = idx >> 5, m = idx & 31;
        float s = 0.f;
        for (int i = 0; i < 32; i++)
            s += bf2f(partKV[((size_t)((b * 32 + i) * 4 + h) << 10) + idx]);
        KVt[((size_t)bh << 10) + m * 32 + d] = f2bf(s);  // [m][d]
    }
    if (t < 32) {
        float s = 0.f;
        for (int i = 0; i < 32; i++)
            for (int w = 0; w < 4; w++)
                s += partKs[((b * 32 + i) * 4 + w) * 128 + h * 32 + t];
        Ksf[bh * 32 + t] = s;
    }
}

// ---------------- k3: fused main with reg-staged weight pipeline ----------------
__global__ __launch_bounds__(256, 2) void k3_main(
    const float* __restrict__ x, const short* __restrict__ Wqt,
    const short* __restrict__ Wot, const short* __restrict__ KVt,
    const float* __restrict__ Ksf, const float* __restrict__ ln1g,
    const float* __restrict__ ln1b, const short* __restrict__ W1t,
    const float* __restrict__ b1, const short* __restrict__ W2t,
    const float* __restrict__ b2, const float* __restrict__ ln2g,
    const float* __restrict__ ln2b, float* __restrict__ out) {
    __shared__ short sbuf[128][136];   // x -> Q -> attn -> y -> h (34.8KB)
    __shared__ short wbuf[2][8192];    // staged weight half-panels (32KB)

    const int t = threadIdx.x, w = t >> 6, l = t & 63, lr = l & 15, lg = l >> 4;
    const int blk = blockIdx.x, b = blk >> 6;
    const size_t tok0 = ((size_t)b << 13) + (size_t)(blk & 63) * 128;
    const int R0 = w * 32;
    const float* xw = x + (tok0 + R0) * 128;
    const ffrag fz = {0.f, 0.f, 0.f, 0.f};

    const int srow0 = w * 4 + (l >> 4);
    const int scol = lr;
    const int cl = scol ^ srow0;
    int4 sg0, sg1, sg2, sg3;

    auto stage_load = [&](const short* src, int rs) {
        sg0 = *(const int4*)(src + (srow0 +  0) * rs + scol * 8);
        sg1 = *(const int4*)(src + (srow0 + 16) * rs + scol * 8);
        sg2 = *(const int4*)(src + (srow0 + 32) * rs + scol * 8);
        sg3 = *(const int4*)(src + (srow0 + 48) * rs + scol * 8);
    };
    auto stage_write = [&](short* wb) {
        *(int4*)(wb + (srow0 +  0) * 128 + cl * 8) = sg0;
        *(int4*)(wb + (srow0 + 16) * 128 + cl * 8) = sg1;
        *(int4*)(wb + (srow0 + 32) * 128 + cl * 8) = sg2;
        *(int4*)(wb + (srow0 + 48) * 128 + cl * 8) = sg3;
    };

    bfrag bI0 = {0, 0, 0, 0, 0, 0, 0, 0}, bI1 = {0, 0, 0, 0, 0, 0, 0, 0};
    {
        const short one = (short)0x3F80;  // bf16 1.0
#pragma unroll
        for (int ee = 0; ee < 8; ee++) {
            bI0[ee] = (ee == (lr & 7) && lg == (lr >> 3)) ? one : (short)0;
            bI1[ee] = (ee == (lr & 7) && lg == 2 + (lr >> 3)) ? one : (short)0;
        }
    }

    bfrag xf[2][4], af[2][4], yf[2][4], hf[2][4];
    float r[2][8][4];
    float mu[2][4], rs[2][4];
    ffrag facc[2][8];

    auto wfrag = [&](const short* wb, int q, int kk) -> bfrag {
        return *(const bfrag*)(wb + (q * 16 + lr) * 128 + (((kk * 4 + lg) ^ lr) * 8));
    };

    auto q_half = [&](const short* wb, int h) {
        __builtin_amdgcn_s_setprio(1);
#pragma unroll
        for (int q = 0; q < 4; q++) {
            int n0 = h * 4 + q;
            ffrag c0 = fz, c1 = fz;
#pragma unroll
            for (int kk = 0; kk < 4; kk++) {
                bfrag bw = wfrag(wb, q, kk);
                c0 = MFMA(xf[0][kk], bw, c0);
                c1 = MFMA(xf[1][kk], bw, c1);
            }
#pragma unroll
            for (int j = 0; j < 4; j++) {
                sbuf[R0 + lg * 4 + j][n0 * 16 + lr] = f2bf(phi_fn(c0[j]));
                sbuf[R0 + 16 + lg * 4 + j][n0 * 16 + lr] = f2bf(phi_fn(c1[j]));
            }
        }
        __builtin_amdgcn_s_setprio(0);
    };
    auto wo_half = [&](const short* wb, int h) {
        __builtin_amdgcn_s_setprio(1);
#pragma unroll
        for (int q = 0; q < 4; q++) {
            int n0 = h * 4 + q;
            const bfrag bIn = (n0 & 1) ? bI1 : bI0;
            ffrag c0 = MFMA(xf[0][n0 >> 1], bIn, fz);  // residual1: x in C-layout
            ffrag c1 = MFMA(xf[1][n0 >> 1], bIn, fz);
#pragma unroll
            for (int kk = 0; kk < 4; kk++) {
                bfrag bw = wfrag(wb, q, kk);
                c0 = MFMA(af[0][kk], bw, c0);
                c1 = MFMA(af[1][kk], bw, c1);
            }
#pragma unroll
            for (int j = 0; j < 4; j++) { r[0][n0][j] = c0[j]; r[1][n0][j] = c1[j]; }
        }
        __builtin_amdgcn_s_setprio(0);
    };
    auto ff1_half = [&](const short* wb, int ch, int h) {
        __builtin_amdgcn_s_setprio(1);
#pragma unroll
        for (int q = 0; q < 4; q++) {
            int n0 = h * 4 + q;
            ffrag c0 = fz, c1 = fz;
#pragma unroll
            for (int kk = 0; kk < 4; kk++) {
                bfrag bw = wfrag(wb, q, kk);
                c0 = MFMA(yf[0][kk], bw, c0);
                c1 = MFMA(yf[1][kk], bw, c1);
            }
            float bb = b1[ch * 128 + n0 * 16 + lr];
#pragma unroll
            for (int j = 0; j < 4; j++) {
                sbuf[R0 + lg * 4 + j][n0 * 16 + lr] = f2bf(fmaxf(c0[j] + bb, 0.f));
                sbuf[R0 + 16 + lg * 4 + j][n0 * 16 + lr] = f2bf(fmaxf(c1[j] + bb, 0.f));
            }
        }
        __builtin_amdgcn_s_setprio(0);
    };
    auto ff2_half = [&](const short* wb, int h) {
        __builtin_amdgcn_s_setprio(1);
#pragma unroll
        for (int q = 0; q < 4; q++) {
            int n0 = h * 4 + q;
#pragma unroll
            for (int kk = 0; kk < 4; kk++) {
                bfrag bw = wfrag(wb, q, kk);
                facc[0][n0] = MFMA(hf[0][kk], bw, facc[0][n0]);
                facc[1][n0] = MFMA(hf[1][kk], bw, facc[1][n0]);
            }
        }
        __builtin_amdgcn_s_setprio(0);
    };

    // ================= S0: x staging + stage Wq h0 =================
    stage_load(Wqt, 128);
#pragma unroll
    for (int it = 0; it < 8; ++it) {
        int idx = it * 64 + l, row = idx >> 4, c8 = (idx & 15) * 8;
        const float4* p = (const float4*)(xw + row * 128 + c8);
        float4 v0 = p[0], v1 = p[1];
        bfrag sv;
        sv[0] = f2bf(v0.x); sv[1] = f2bf(v0.y); sv[2] = f2bf(v0.z); sv[3] = f2bf(v0.w);
        sv[4] = f2bf(v1.x); sv[5] = f2bf(v1.y); sv[6] = f2bf(v1.z); sv[7] = f2bf(v1.w);
        *(bfrag*)&sbuf[R0 + row][c8] = sv;
    }
    stage_write(wbuf[0]);
    stage_load(Wqt + 64 * 128, 128);  // m1 = Wq h1
    __syncthreads();

    // ================= S1: Q h0 =================
    stage_write(wbuf[1]);
    stage_load(Wot, 128);             // m2 = Wo h0
#pragma unroll
    for (int rt = 0; rt < 2; rt++)
#pragma unroll
        for (int kk = 0; kk < 4; kk++)
            xf[rt][kk] = *(const bfrag*)&sbuf[R0 + rt * 16 + lr][kk * 32 + lg * 8];
    q_half(wbuf[0], 0);
    __syncthreads();

    // ================= S2: Q h1 =================
    stage_write(wbuf[0]);
    stage_load(Wot + 64 * 128, 128);  // m3 = Wo h1
    q_half(wbuf[1], 1);
    __syncthreads();

    // ================= S3: attn + Wo h0 =================
    stage_write(wbuf[1]);
    stage_load(W1t, 128);             // m4 = W1c0 h0
#pragma unroll
    for (int h = 0; h < 4; h++) {
        bfrag qf0 = *(const bfrag*)&sbuf[R0 + lr][h * 32 + lg * 8];
        bfrag qf1 = *(const bfrag*)&sbuf[R0 + 16 + lr][h * 32 + lg * 8];
        const float4* kp = (const float4*)(Ksf + (b * 4 + h) * 32 + lg * 8);
        float4 ka = kp[0], kb = kp[1];
        float ksv[8] = {ka.x, ka.y, ka.z, ka.w, kb.x, kb.y, kb.z, kb.w};
        float p0 = 0.f, p1 = 0.f;
#pragma unroll
        for (int j = 0; j < 8; j++) {
            p0 += bf2f(qf0[j]) * ksv[j];
            p1 += bf2f(qf1[j]) * ksv[j];
        }
        p0 += __shfl_xor(p0, 16); p0 += __shfl_xor(p0, 32);
        p1 += __shfl_xor(p1, 16); p1 += __shfl_xor(p1, 32);
        float rd0 = __builtin_amdgcn_rcpf(fmaxf(p0, 1e-6f));
        float rd1 = __builtin_amdgcn_rcpf(fmaxf(p1, 1e-6f));
        float dv0[4], dv1[4];
#pragma unroll
        for (int j = 0; j < 4; j++) {
            dv0[j] = __shfl(rd0, lg * 4 + j);
            dv1[j] = __shfl(rd1, lg * 4 + j);
        }
        __builtin_amdgcn_s_setprio(1);
#pragma unroll
        for (int mt = 0; mt < 2; mt++) {
            bfrag bkv = *(const bfrag*)(KVt + ((size_t)(b * 4 + h) << 10) + (mt * 16 + lr) * 32 + lg * 8);
            ffrag c0 = MFMA(qf0, bkv, fz);
            ffrag c1 = MFMA(qf1, bkv, fz);
#pragma unroll
            for (int j = 0; j < 4; j++) {
                sbuf[R0 + lg * 4 + j][h * 32 + mt * 16 + lr] = f2bf(c0[j] * dv0[j]);
                sbuf[R0 + 16 + lg * 4 + j][h * 32 + mt * 16 + lr] = f2bf(c1[j] * dv1[j]);
            }
        }
        __builtin_amdgcn_s_setprio(0);
    }
#pragma unroll
    for (int rt = 0; rt < 2; rt++)
#pragma unroll
        for (int kk = 0; kk < 4; kk++)
            af[rt][kk] = *(const bfrag*)&sbuf[R0 + rt * 16 + lr][kk * 32 + lg * 8];
    wo_half(wbuf[0], 0);
    __syncthreads();

    // ================= S4: Wo h1 =================
    stage_write(wbuf[0]);
    stage_load(W1t + 64 * 128, 128);  // m5 = W1c0 h1
    wo_half(wbuf[1], 1);
    __syncthreads();

    // ================= ch loop: 4 segments per ch =================
    for (int ch = 0; ch < 4; ++ch) {
        // --- A: FF1 ch h0 ---
        stage_write(wbuf[1]);                       // W1ch h1
        stage_load(W2t + ch * 128, 512);            // W2ch h0
        if (ch == 0) {
#pragma unroll
            for (int rt = 0; rt < 2; rt++)
#pragma unroll
                for (int j = 0; j < 4; j++) {
                    float s1 = 0.f, s2 = 0.f;
#pragma unroll
                    for (int n0 = 0; n0 < 8; n0++) { float v = r[rt][n0][j]; s1 += v; s2 += v * v; }
#pragma unroll
                    for (int d = 1; d < 16; d <<= 1) { s1 += __shfl_xor(s1, d); s2 += __shfl_xor(s2, d); }
                    float m_ = s1 * (1.f / 128.f);
                    mu[rt][j] = m_;
                    rs[rt][j] = rsqrtf(s2 * (1.f / 128.f) - m_ * m_ + 1e-5f);
                }
#pragma unroll
            for (int n0 = 0; n0 < 8; n0++) {
                int c = n0 * 16 + lr;
                float g = ln1g[c], bb = ln1b[c];
#pragma unroll
                for (int rt = 0; rt < 2; rt++)
#pragma unroll
                    for (int j = 0; j < 4; j++) {
                        int row = R0 + rt * 16 + lg * 4 + j;
                        sbuf[row][c] = f2bf((r[rt][n0][j] - mu[rt][j]) * rs[rt][j] * g + bb);
                    }
            }
#pragma unroll
            for (int rt = 0; rt < 2; rt++)
#pragma unroll
                for (int kk = 0; kk < 4; kk++)
                    yf[rt][kk] = *(const bfrag*)&sbuf[R0 + rt * 16 + lr][kk * 32 + lg * 8];
#pragma unroll
            for (int rt = 0; rt < 2; rt++)
#pragma unroll
                for (int n0 = 0; n0 < 8; n0++) {
                    const bfrag bIn = (n0 & 1) ? bI1 : bI0;
                    facc[rt][n0] = MFMA(yf[rt][n0 >> 1], bIn, fz);  // residual2
                }
        }
        ff1_half(wbuf[0], ch, 0);
        __syncthreads();

        // --- B: FF1 ch h1 ---
        stage_write(wbuf[0]);                       // W2ch h0
        stage_load(W2t + ch * 128 + 64 * 512, 512); // W2ch h1
        ff1_half(wbuf[1], ch, 1);
        __syncthreads();

        // --- C: FF2 ch h0 ---
        stage_write(wbuf[1]);                       // W2ch h1
        if (ch < 3) stage_load(W1t + ((ch + 1) * 128) * 128, 128);
#pragma unroll
        for (int rt = 0; rt < 2; rt++)
#pragma unroll
            for (int kk = 0; kk < 4; kk++)
                hf[rt][kk] = *(const bfrag*)&sbuf[R0 + rt * 16 + lr][kk * 32 + lg * 8];
        ff2_half(wbuf[0], 0);
        __syncthreads();

        // --- D: FF2 ch h1 ---
        if (ch < 3) {
            stage_write(wbuf[0]);
            stage_load(W1t + ((ch + 1) * 128 + 64) * 128, 128);
        }
        ff2_half(wbuf[1], 1);
        if (ch < 3) __syncthreads();
    }

    // ================= epilogue: +b2, LN2, store =================
#pragma unroll
    for (int n0 = 0; n0 < 8; n0++) {
        float bb = b2[n0 * 16 + lr];
#pragma unroll
        for (int rt = 0; rt < 2; rt++)
#pragma unroll
            for (int j = 0; j < 4; j++) facc[rt][n0][j] += bb;
    }
    float mu2[2][4], rs2[2][4];
#pragma unroll
    for (int rt = 0; rt < 2; rt++)
#pragma unroll
        for (int j = 0; j < 4; j++) {
            float s1 = 0.f, s2 = 0.f;
#pragma unroll
            for (int n0 = 0; n0 < 8; n0++) { float v = facc[rt][n0][j]; s1 += v; s2 += v * v; }
#pragma unroll
            for (int d = 1; d < 16; d <<= 1) { s1 += __shfl_xor(s1, d); s2 += __shfl_xor(s2, d); }
            float m_ = s1 * (1.f / 128.f);
            mu2[rt][j] = m_;
            rs2[rt][j] = rsqrtf(s2 * (1.f / 128.f) - m_ * m_ + 1e-5f);
        }
#pragma unroll
    for (int n0 = 0; n0 < 8; n0++) {
        int c = n0 * 16 + lr;
        float g = ln2g[c], bb = ln2b[c];
#pragma unroll
        for (int rt = 0; rt < 2; rt++)
#pragma unroll
            for (int j = 0; j < 4; j++) {
                int row = R0 + rt * 16 + lg * 4 + j;
                out[(tok0 + row) * 128 + c] = (facc[rt][n0][j] - mu2[rt][j]) * rs2[rt][j] * g + bb;
            }
    }
}

extern "C" void kernel_launch(void* const* d_in, const int* in_sizes, int n_in,
                              void* d_out, int out_size, void* d_ws, size_t ws_size,
                              hipStream_t stream) {
    const float* x    = (const float*)d_in[0];
    const float* Wq   = (const float*)d_in[1];
    const float* Wk   = (const float*)d_in[2];
    const float* Wv   = (const float*)d_in[3];
    const float* Wo   = (const float*)d_in[4];
    const float* ln1g = (const float*)d_in[5];
    const float* ln1b = (const float*)d_in[6];
    const float* W1   = (const float*)d_in[7];
    const float* b1   = (const float*)d_in[8];
    const float* W2   = (const float*)d_in[9];
    const float* b2   = (const float*)d_in[10];
    const float* ln2g = (const float*)d_in[11];
    const float* ln2b = (const float*)d_in[12];
    float* out = (float*)d_out;

    // ws layout (~5.7 MB)
    short* partKV = (short*)d_ws;                       // 512*4*1024 bf16
    float* partKs = (float*)(partKV + 2097152);         // 512*4*128  f32
    short* KVt    = (short*)(partKs + 262144);          // 64*1024    bf16 [m][d]
    float* Ksf    = (float*)(KVt + 65536);              // 64*32      f32
    short* Wqt    = (short*)(Ksf + 2048);
    short* Wkt    = Wqt + 16384;
    short* Wvt    = Wkt + 16384;
    short* Wot    = Wvt + 16384;
    short* W1t    = Wot + 16384;                        // [512][128]
    short* W2t    = W1t + 65536;                        // [128][512]

    kw_conv<<<768, 256, 0, stream>>>(Wq, Wk, Wv, Wo, W1, W2, Wqt, Wkt, Wvt, Wot, W1t, W2t);
    k1_kv<<<512, 256, 0, stream>>>(x, Wkt, Wvt, partKV, partKs);
    k2_red<<<64, 256, 0, stream>>>(partKV, partKs, KVt, Ksf);
    k3_main<<<1024, 256, 0, stream>>>(x, Wqt, Wot, KVt, Ksf, ln1g, ln1b, W1t, b1,
                                      W2t, b2, ln2g, ln2b, out);
}

// Round 13
// 121.815 us; speedup vs baseline: 1.0387x; 1.0387x over previous
//
#include <hip/hip_runtime.h>
#include <math.h>

// LinearAttentionBlock — bf16 MFMA v12: r9's k1/k2/kw + k3 widened to
// 512 threads / 256 tokens per block (8 waves, 1 block/CU) so the 21-segment
// weight pipeline amortizes over 2x tokens (barriers/token and staging/token
// halve). Per-wave compute identical to r9 (numerics unchanged).
// B=16, N=8192, D=128, H=4, dh=32, FF=512. mfma_f32_16x16x32_bf16.

using bfrag = __attribute__((ext_vector_type(8))) short;   // 8 bf16 (MFMA A/B)
using sh4   = __attribute__((ext_vector_type(4))) short;   // 4 bf16
using ffrag = __attribute__((ext_vector_type(4))) float;   // MFMA C/D

#define MFMA(a, b, c) __builtin_amdgcn_mfma_f32_16x16x32_bf16((a), (b), (c), 0, 0, 0)

__device__ __forceinline__ float phi_fn(float v) { return v > 0.f ? v + 1.f : __expf(v); }

// native bf16 convert (RNE) — compiler emits v_cvt_pk_bf16_f32 for pairs
__device__ __forceinline__ short f2bf(float f) {
    __bf16 h = (__bf16)f;
    return *(short*)&h;
}
__device__ __forceinline__ float bf2f(short s) {
    union { unsigned u; float f; } v; v.u = ((unsigned)(unsigned short)s) << 16;
    return v.f;
}

// ---------------- kw: weight convert + transpose ----------------
__global__ void kw_conv(const float* __restrict__ Wq, const float* __restrict__ Wk,
                        const float* __restrict__ Wv, const float* __restrict__ Wo,
                        const float* __restrict__ W1, const float* __restrict__ W2,
                        short* __restrict__ Wqt, short* __restrict__ Wkt,
                        short* __restrict__ Wvt, short* __restrict__ Wot,
                        short* __restrict__ W1t, short* __restrict__ W2t) {
    int i = blockIdx.x * 256 + threadIdx.x;
    if (i < 65536) {
        int mat = i >> 14, q = i & 16383, n = q >> 7, k = q & 127;
        const float* S = mat == 0 ? Wq : mat == 1 ? Wk : mat == 2 ? Wv : Wo;
        short* D = mat == 0 ? Wqt : mat == 1 ? Wkt : mat == 2 ? Wvt : Wot;
        D[n * 128 + k] = f2bf(S[k * 128 + n]);
    } else if (i < 131072) {
        int q = i - 65536, n = q >> 7, k = q & 127;
        W1t[n * 128 + k] = f2bf(W1[k * 512 + n]);
    } else {
        int q = i - 131072, n = q >> 9, k = q & 511;
        W2t[n * 512 + k] = f2bf(W2[k * 128 + n]);
    }
}

// ---------------- k1 v2: K/V proj + partial KV, staged-weight pipeline (r8-proven) ----------------
__global__ __launch_bounds__(256, 2) void k1_kv(
    const float* __restrict__ x, const short* __restrict__ Wkt,
    const short* __restrict__ Wvt, short* __restrict__ partKV,
    float* __restrict__ partKs) {
    __shared__ short sx[64][136];   // 17.4KB
    __shared__ short Kt[128][72];   // 18.4KB [dim][token]
    __shared__ short Vt[128][72];   // 18.4KB
    __shared__ short wbuf[8192];    // 16KB: one 64x128 half-panel, chunk-swizzled

    const int t = threadIdx.x, w = t >> 6, l = t & 63, lr = l & 15, lg = l >> 4;
    const int blk = blockIdx.x, b = blk >> 5;
    const size_t tok0 = ((size_t)b << 13) + (size_t)(blk & 31) * 256;
    const ffrag fz = {0.f, 0.f, 0.f, 0.f};

    const int srow0 = w * 4 + (l >> 4);  // 0..15; rows srow0+{0,16,32,48}
    const int scol = lr;
    const int cl = scol ^ srow0;
    int4 sg0, sg1, sg2, sg3;
    auto stage_load = [&](const short* src) {
        sg0 = *(const int4*)(src + (srow0 +  0) * 128 + scol * 8);
        sg1 = *(const int4*)(src + (srow0 + 16) * 128 + scol * 8);
        sg2 = *(const int4*)(src + (srow0 + 32) * 128 + scol * 8);
        sg3 = *(const int4*)(src + (srow0 + 48) * 128 + scol * 8);
    };
    auto stage_write = [&]() {
        *(int4*)(wbuf + (srow0 +  0) * 128 + cl * 8) = sg0;
        *(int4*)(wbuf + (srow0 + 16) * 128 + cl * 8) = sg1;
        *(int4*)(wbuf + (srow0 + 32) * 128 + cl * 8) = sg2;
        *(int4*)(wbuf + (srow0 + 48) * 128 + cl * 8) = sg3;
    };
    auto wfrag = [&](int q, int kk) -> bfrag {
        return *(const bfrag*)(wbuf + (q * 16 + lr) * 128 + (((kk * 4 + lg) ^ lr) * 8));
    };

    ffrag kvacc[2][2];
#pragma unroll
    for (int dt = 0; dt < 2; dt++)
#pragma unroll
        for (int mt = 0; mt < 2; mt++) kvacc[dt][mt] = fz;
    float accKs[8];
#pragma unroll
    for (int i = 0; i < 8; i++) accKs[i] = 0.f;

    stage_load(Wkt);  // panel 0 = Wk h0

    for (int s = 0; s < 4; ++s) {
        const float* xb = x + (tok0 + (size_t)s * 64 + w * 16) * 128;
#pragma unroll
        for (int it = 0; it < 4; ++it) {
            int idx = it * 64 + l, row = idx >> 4, c8 = (idx & 15) * 8;
            const float4* p = (const float4*)(xb + row * 128 + c8);
            float4 v0 = p[0], v1 = p[1];
            bfrag sv;
            sv[0] = f2bf(v0.x); sv[1] = f2bf(v0.y); sv[2] = f2bf(v0.z); sv[3] = f2bf(v0.w);
            sv[4] = f2bf(v1.x); sv[5] = f2bf(v1.y); sv[6] = f2bf(v1.z); sv[7] = f2bf(v1.w);
            *(bfrag*)&sx[w * 16 + row][c8] = sv;
        }
        bfrag xf[4];
#pragma unroll
        for (int kk = 0; kk < 4; kk++)
            xf[kk] = *(const bfrag*)&sx[w * 16 + lr][kk * 32 + lg * 8];
        const int toff = w * 16 + lg * 4;

        // 4 weight segments: p = 0:Wk h0, 1:Wk h1, 2:Wv h0, 3:Wv h1
#pragma unroll
        for (int p = 0; p < 4; ++p) {
            __syncthreads();   // prior wbuf readers done
            stage_write();
            int nseg = s * 4 + p + 1;
            if (nseg < 16) {
                const short* nsrc = ((nseg & 2) ? Wvt : Wkt) + ((nseg & 1) ? 8192 : 0);
                stage_load(nsrc);
            }
            __syncthreads();   // wbuf ready
            const int half = p & 1;
#pragma unroll
            for (int q = 0; q < 4; q++) {
                const int n0 = half * 4 + q;
                ffrag c = fz;
#pragma unroll
                for (int kk = 0; kk < 4; kk++) c = MFMA(xf[kk], wfrag(q, kk), c);
                if (p < 2) {  // K: phi + Ksum + Kt
                    sh4 ks;
#pragma unroll
                    for (int j = 0; j < 4; j++) {
                        float pv = phi_fn(c[j]);
                        accKs[n0] += pv;
                        ks[j] = f2bf(pv);
                    }
                    *(sh4*)&Kt[n0 * 16 + lr][toff] = ks;
                } else {      // V
                    sh4 vs;
#pragma unroll
                    for (int j = 0; j < 4; j++) vs[j] = f2bf(c[j]);
                    *(sh4*)&Vt[n0 * 16 + lr][toff] = vs;
                }
            }
        }
        __syncthreads();  // Kt/Vt complete for this subtile

#pragma unroll
        for (int kk = 0; kk < 2; kk++) {
            bfrag ka0 = *(const bfrag*)&Kt[w * 32 + lr][kk * 32 + lg * 8];
            bfrag ka1 = *(const bfrag*)&Kt[w * 32 + 16 + lr][kk * 32 + lg * 8];
            bfrag vb0 = *(const bfrag*)&Vt[w * 32 + lr][kk * 32 + lg * 8];
            bfrag vb1 = *(const bfrag*)&Vt[w * 32 + 16 + lr][kk * 32 + lg * 8];
            kvacc[0][0] = MFMA(ka0, vb0, kvacc[0][0]);
            kvacc[0][1] = MFMA(ka0, vb1, kvacc[0][1]);
            kvacc[1][0] = MFMA(ka1, vb0, kvacc[1][0]);
            kvacc[1][1] = MFMA(ka1, vb1, kvacc[1][1]);
        }
    }
    short* pk = partKV + ((size_t)(blk * 4 + w) << 10);
#pragma unroll
    for (int dt = 0; dt < 2; dt++)
#pragma unroll
        for (int mt = 0; mt < 2; mt++)
#pragma unroll
            for (int j = 0; j < 4; j++)
                pk[(dt * 16 + lg * 4 + j) * 32 + mt * 16 + lr] = f2bf(kvacc[dt][mt][j]);
#pragma unroll
    for (int n0 = 0; n0 < 8; n0++) {
        float v = accKs[n0];
        v += __shfl_xor(v, 16);
        v += __shfl_xor(v, 32);
        if (l < 16) partKs[(blk * 4 + w) * 128 + n0 * 16 + l] = v;
    }
}

// ---------------- k2: reduce partials ----------------
__global__ void k2_red(const short* __restrict__ partKV, const float* __restrict__ partKs,
                       short* __restrict__ KVt, float* __restrict__ Ksf) {
    int bh = blockIdx.x, b = bh >> 2, h = bh & 3, t = threadIdx.x;
    for (int idx = t; idx < 1024; idx += 256) {
        int d = idx >> 5, m = idx & 31;
        float s = 0.f;
        for (int i = 0; i < 32; i++)
            s += bf2f(partKV[((size_t)((b * 32 + i) * 4 + h) << 10) + idx]);
        KVt[((size_t)bh << 10) + m * 32 + d] = f2bf(s);  // [m][d]
    }
    if (t < 32) {
        float s = 0.f;
        for (int i = 0; i < 32; i++)
            for (int w = 0; w < 4; w++)
                s += partKs[((b * 32 + i) * 4 + w) * 128 + h * 32 + t];
        Ksf[bh * 32 + t] = s;
    }
}

// ---------------- k3: fused main, 512 thr / 256 tokens / 8 waves ----------------
// 512 blocks; wave w (0..7) owns rows 32w..32w+31 of the 256-token tile.
// Same 21-segment reg-staged weight pipeline as r9, amortized over 2x tokens.
__global__ __launch_bounds__(512, 2) void k3_main(
    const float* __restrict__ x, const short* __restrict__ Wqt,
    const short* __restrict__ Wot, const short* __restrict__ KVt,
    const float* __restrict__ Ksf, const float* __restrict__ ln1g,
    const float* __restrict__ ln1b, const short* __restrict__ W1t,
    const float* __restrict__ b1, const short* __restrict__ W2t,
    const float* __restrict__ b2, const float* __restrict__ ln2g,
    const float* __restrict__ ln2b, float* __restrict__ out) {
    __shared__ short sbuf[256][136];   // x -> Q -> attn -> y -> h (69.6KB)
    __shared__ short wbuf[2][8192];    // staged weight half-panels (32KB)

    const int t = threadIdx.x, w = t >> 6, l = t & 63, lr = l & 15, lg = l >> 4;
    const int blk = blockIdx.x, b = blk >> 5;
    const size_t tok0 = ((size_t)b << 13) + (size_t)(blk & 31) * 256;
    const int R0 = w * 32;
    const float* xw = x + (tok0 + R0) * 128;
    const ffrag fz = {0.f, 0.f, 0.f, 0.f};

    // staging over 512 threads: thread covers rows {srow0, srow0+32}, chunk scol
    const int srow0 = t >> 4;          // 0..31
    const int scol = t & 15;
    const int cl = scol ^ (srow0 & 15);  // (srow0+32)&15 == srow0&15 -> same cl
    int4 sg0, sg1;

    auto stage_load = [&](const short* src, int rs) {
        sg0 = *(const int4*)(src + (size_t)(srow0     ) * rs + scol * 8);
        sg1 = *(const int4*)(src + (size_t)(srow0 + 32) * rs + scol * 8);
    };
    auto stage_write = [&](short* wb) {
        *(int4*)(wb + (srow0     ) * 128 + cl * 8) = sg0;
        *(int4*)(wb + (srow0 + 32) * 128 + cl * 8) = sg1;
    };

    bfrag bI0 = {0, 0, 0, 0, 0, 0, 0, 0}, bI1 = {0, 0, 0, 0, 0, 0, 0, 0};
    {
        const short one = (short)0x3F80;  // bf16 1.0
#pragma unroll
        for (int ee = 0; ee < 8; ee++) {
            bI0[ee] = (ee == (lr & 7) && lg == (lr >> 3)) ? one : (short)0;
            bI1[ee] = (ee == (lr & 7) && lg == 2 + (lr >> 3)) ? one : (short)0;
        }
    }

    bfrag xf[2][4], af[2][4], yf[2][4], hf[2][4];
    float r[2][8][4];
    float mu[2][4], rs[2][4];
    ffrag facc[2][8];

    auto wfrag = [&](const short* wb, int q, int kk) -> bfrag {
        return *(const bfrag*)(wb + (q * 16 + lr) * 128 + (((kk * 4 + lg) ^ lr) * 8));
    };

    auto q_half = [&](const short* wb, int h) {
        __builtin_amdgcn_s_setprio(1);
#pragma unroll
        for (int q = 0; q < 4; q++) {
            int n0 = h * 4 + q;
            ffrag c0 = fz, c1 = fz;
#pragma unroll
            for (int kk = 0; kk < 4; kk++) {
                bfrag bw = wfrag(wb, q, kk);
                c0 = MFMA(xf[0][kk], bw, c0);
                c1 = MFMA(xf[1][kk], bw, c1);
            }
#pragma unroll
            for (int j = 0; j < 4; j++) {
                sbuf[R0 + lg * 4 + j][n0 * 16 + lr] = f2bf(phi_fn(c0[j]));
                sbuf[R0 + 16 + lg * 4 + j][n0 * 16 + lr] = f2bf(phi_fn(c1[j]));
            }
        }
        __builtin_amdgcn_s_setprio(0);
    };
    auto wo_half = [&](const short* wb, int h) {
        __builtin_amdgcn_s_setprio(1);
#pragma unroll
        for (int q = 0; q < 4; q++) {
            int n0 = h * 4 + q;
            const bfrag bIn = (n0 & 1) ? bI1 : bI0;
            ffrag c0 = MFMA(xf[0][n0 >> 1], bIn, fz);  // residual1: x in C-layout
            ffrag c1 = MFMA(xf[1][n0 >> 1], bIn, fz);
#pragma unroll
            for (int kk = 0; kk < 4; kk++) {
                bfrag bw = wfrag(wb, q, kk);
                c0 = MFMA(af[0][kk], bw, c0);
                c1 = MFMA(af[1][kk], bw, c1);
            }
#pragma unroll
            for (int j = 0; j < 4; j++) { r[0][n0][j] = c0[j]; r[1][n0][j] = c1[j]; }
        }
        __builtin_amdgcn_s_setprio(0);
    };
    auto ff1_half = [&](const short* wb, int ch, int h) {
        __builtin_amdgcn_s_setprio(1);
#pragma unroll
        for (int q = 0; q < 4; q++) {
            int n0 = h * 4 + q;
            ffrag c0 = fz, c1 = fz;
#pragma unroll
            for (int kk = 0; kk < 4; kk++) {
                bfrag bw = wfrag(wb, q, kk);
                c0 = MFMA(yf[0][kk], bw, c0);
                c1 = MFMA(yf[1][kk], bw, c1);
            }
            float bb = b1[ch * 128 + n0 * 16 + lr];
#pragma unroll
            for (int j = 0; j < 4; j++) {
                sbuf[R0 + lg * 4 + j][n0 * 16 + lr] = f2bf(fmaxf(c0[j] + bb, 0.f));
                sbuf[R0 + 16 + lg * 4 + j][n0 * 16 + lr] = f2bf(fmaxf(c1[j] + bb, 0.f));
            }
        }
        __builtin_amdgcn_s_setprio(0);
    };
    auto ff2_half = [&](const short* wb, int h) {
        __builtin_amdgcn_s_setprio(1);
#pragma unroll
        for (int q = 0; q < 4; q++) {
            int n0 = h * 4 + q;
#pragma unroll
            for (int kk = 0; kk < 4; kk++) {
                bfrag bw = wfrag(wb, q, kk);
                facc[0][n0] = MFMA(hf[0][kk], bw, facc[0][n0]);
                facc[1][n0] = MFMA(hf[1][kk], bw, facc[1][n0]);
            }
        }
        __builtin_amdgcn_s_setprio(0);
    };

    // ================= S0: x staging + stage Wq h0 =================
    stage_load(Wqt, 128);
#pragma unroll
    for (int it = 0; it < 8; ++it) {
        int idx = it * 64 + l, row = idx >> 4, c8 = (idx & 15) * 8;
        const float4* p = (const float4*)(xw + row * 128 + c8);
        float4 v0 = p[0], v1 = p[1];
        bfrag sv;
        sv[0] = f2bf(v0.x); sv[1] = f2bf(v0.y); sv[2] = f2bf(v0.z); sv[3] = f2bf(v0.w);
        sv[4] = f2bf(v1.x); sv[5] = f2bf(v1.y); sv[6] = f2bf(v1.z); sv[7] = f2bf(v1.w);
        *(bfrag*)&sbuf[R0 + row][c8] = sv;
    }
    stage_write(wbuf[0]);
    stage_load(Wqt + 64 * 128, 128);  // m1 = Wq h1
    __syncthreads();

    // ================= S1: Q h0 =================
    stage_write(wbuf[1]);
    stage_load(Wot, 128);             // m2 = Wo h0
#pragma unroll
    for (int rt = 0; rt < 2; rt++)
#pragma unroll
        for (int kk = 0; kk < 4; kk++)
            xf[rt][kk] = *(const bfrag*)&sbuf[R0 + rt * 16 + lr][kk * 32 + lg * 8];
    q_half(wbuf[0], 0);
    __syncthreads();

    // ================= S2: Q h1 =================
    stage_write(wbuf[0]);
    stage_load(Wot + 64 * 128, 128);  // m3 = Wo h1
    q_half(wbuf[1], 1);
    __syncthreads();

    // ================= S3: attn + Wo h0 =================
    stage_write(wbuf[1]);
    stage_load(W1t, 128);             // m4 = W1c0 h0
#pragma unroll
    for (int h = 0; h < 4; h++) {
        bfrag qf0 = *(const bfrag*)&sbuf[R0 + lr][h * 32 + lg * 8];
        bfrag qf1 = *(const bfrag*)&sbuf[R0 + 16 + lr][h * 32 + lg * 8];
        const float4* kp = (const float4*)(Ksf + (b * 4 + h) * 32 + lg * 8);
        float4 ka = kp[0], kb = kp[1];
        float ksv[8] = {ka.x, ka.y, ka.z, ka.w, kb.x, kb.y, kb.z, kb.w};
        float p0 = 0.f, p1 = 0.f;
#pragma unroll
        for (int j = 0; j < 8; j++) {
            p0 += bf2f(qf0[j]) * ksv[j];
            p1 += bf2f(qf1[j]) * ksv[j];
        }
        p0 += __shfl_xor(p0, 16); p0 += __shfl_xor(p0, 32);
        p1 += __shfl_xor(p1, 16); p1 += __shfl_xor(p1, 32);
        float rd0 = __builtin_amdgcn_rcpf(fmaxf(p0, 1e-6f));
        float rd1 = __builtin_amdgcn_rcpf(fmaxf(p1, 1e-6f));
        float dv0[4], dv1[4];
#pragma unroll
        for (int j = 0; j < 4; j++) {
            dv0[j] = __shfl(rd0, lg * 4 + j);
            dv1[j] = __shfl(rd1, lg * 4 + j);
        }
        __builtin_amdgcn_s_setprio(1);
#pragma unroll
        for (int mt = 0; mt < 2; mt++) {
            bfrag bkv = *(const bfrag*)(KVt + ((size_t)(b * 4 + h) << 10) + (mt * 16 + lr) * 32 + lg * 8);
            ffrag c0 = MFMA(qf0, bkv, fz);
            ffrag c1 = MFMA(qf1, bkv, fz);
#pragma unroll
            for (int j = 0; j < 4; j++) {
                sbuf[R0 + lg * 4 + j][h * 32 + mt * 16 + lr] = f2bf(c0[j] * dv0[j]);
                sbuf[R0 + 16 + lg * 4 + j][h * 32 + mt * 16 + lr] = f2bf(c1[j] * dv1[j]);
            }
        }
        __builtin_amdgcn_s_setprio(0);
    }
#pragma unroll
    for (int rt = 0; rt < 2; rt++)
#pragma unroll
        for (int kk = 0; kk < 4; kk++)
            af[rt][kk] = *(const bfrag*)&sbuf[R0 + rt * 16 + lr][kk * 32 + lg * 8];
    wo_half(wbuf[0], 0);
    __syncthreads();

    // ================= S4: Wo h1 =================
    stage_write(wbuf[0]);
    stage_load(W1t + 64 * 128, 128);  // m5 = W1c0 h1
    wo_half(wbuf[1], 1);
    __syncthreads();

    // ================= ch loop: 4 segments per ch =================
    for (int ch = 0; ch < 4; ++ch) {
        // --- A: FF1 ch h0 ---
        stage_write(wbuf[1]);                       // W1ch h1
        stage_load(W2t + ch * 128, 512);            // W2ch h0
        if (ch == 0) {
#pragma unroll
            for (int rt = 0; rt < 2; rt++)
#pragma unroll
                for (int j = 0; j < 4; j++) {
                    float s1 = 0.f, s2 = 0.f;
#pragma unroll
                    for (int n0 = 0; n0 < 8; n0++) { float v = r[rt][n0][j]; s1 += v; s2 += v * v; }
#pragma unroll
                    for (int d = 1; d < 16; d <<= 1) { s1 += __shfl_xor(s1, d); s2 += __shfl_xor(s2, d); }
                    float m_ = s1 * (1.f / 128.f);
                    mu[rt][j] = m_;
                    rs[rt][j] = rsqrtf(s2 * (1.f / 128.f) - m_ * m_ + 1e-5f);
                }
#pragma unroll
            for (int n0 = 0; n0 < 8; n0++) {
                int c = n0 * 16 + lr;
                float g = ln1g[c], bb = ln1b[c];
#pragma unroll
                for (int rt = 0; rt < 2; rt++)
#pragma unroll
                    for (int j = 0; j < 4; j++) {
                        int row = R0 + rt * 16 + lg * 4 + j;
                        sbuf[row][c] = f2bf((r[rt][n0][j] - mu[rt][j]) * rs[rt][j] * g + bb);
                    }
            }
#pragma unroll
            for (int rt = 0; rt < 2; rt++)
#pragma unroll
                for (int kk = 0; kk < 4; kk++)
                    yf[rt][kk] = *(const bfrag*)&sbuf[R0 + rt * 16 + lr][kk * 32 + lg * 8];
#pragma unroll
            for (int rt = 0; rt < 2; rt++)
#pragma unroll
                for (int n0 = 0; n0 < 8; n0++) {
                    const bfrag bIn = (n0 & 1) ? bI1 : bI0;
                    facc[rt][n0] = MFMA(yf[rt][n0 >> 1], bIn, fz);  // residual2
                }
        }
        ff1_half(wbuf[0], ch, 0);
        __syncthreads();

        // --- B: FF1 ch h1 ---
        stage_write(wbuf[0]);                       // W2ch h0
        stage_load(W2t + ch * 128 + 64 * 512, 512); // W2ch h1
        ff1_half(wbuf[1], ch, 1);
        __syncthreads();

        // --- C: FF2 ch h0 ---
        stage_write(wbuf[1]);                       // W2ch h1
        if (ch < 3) stage_load(W1t + ((ch + 1) * 128) * 128, 128);
#pragma unroll
        for (int rt = 0; rt < 2; rt++)
#pragma unroll
            for (int kk = 0; kk < 4; kk++)
                hf[rt][kk] = *(const bfrag*)&sbuf[R0 + rt * 16 + lr][kk * 32 + lg * 8];
        ff2_half(wbuf[0], 0);
        __syncthreads();

        // --- D: FF2 ch h1 ---
        if (ch < 3) {
            stage_write(wbuf[0]);
            stage_load(W1t + ((ch + 1) * 128 + 64) * 128, 128);
        }
        ff2_half(wbuf[1], 1);
        if (ch < 3) __syncthreads();
    }

    // ================= epilogue: +b2, LN2, store =================
#pragma unroll
    for (int n0 = 0; n0 < 8; n0++) {
        float bb = b2[n0 * 16 + lr];
#pragma unroll
        for (int rt = 0; rt < 2; rt++)
#pragma unroll
            for (int j = 0; j < 4; j++) facc[rt][n0][j] += bb;
    }
    float mu2[2][4], rs2[2][4];
#pragma unroll
    for (int rt = 0; rt < 2; rt++)
#pragma unroll
        for (int j = 0; j < 4; j++) {
            float s1 = 0.f, s2 = 0.f;
#pragma unroll
            for (int n0 = 0; n0 < 8; n0++) { float v = facc[rt][n0][j]; s1 += v; s2 += v * v; }
#pragma unroll
            for (int d = 1; d < 16; d <<= 1) { s1 += __shfl_xor(s1, d); s2 += __shfl_xor(s2, d); }
            float m_ = s1 * (1.f / 128.f);
            mu2[rt][j] = m_;
            rs2[rt][j] = rsqrtf(s2 * (1.f / 128.f) - m_ * m_ + 1e-5f);
        }
#pragma unroll
    for (int n0 = 0; n0 < 8; n0++) {
        int c = n0 * 16 + lr;
        float g = ln2g[c], bb = ln2b[c];
#pragma unroll
        for (int rt = 0; rt < 2; rt++)
#pragma unroll
            for (int j = 0; j < 4; j++) {
                int row = R0 + rt * 16 + lg * 4 + j;
                out[(tok0 + row) * 128 + c] = (facc[rt][n0][j] - mu2[rt][j]) * rs2[rt][j] * g + bb;
            }
    }
}

extern "C" void kernel_launch(void* const* d_in, const int* in_sizes, int n_in,
                              void* d_out, int out_size, void* d_ws, size_t ws_size,
                              hipStream_t stream) {
    const float* x    = (const float*)d_in[0];
    const float* Wq   = (const float*)d_in[1];
    const float* Wk   = (const float*)d_in[2];
    const float* Wv   = (const float*)d_in[3];
    const float* Wo   = (const float*)d_in[4];
    const float* ln1g = (const float*)d_in[5];
    const float* ln1b = (const float*)d_in[6];
    const float* W1   = (const float*)d_in[7];
    const float* b1   = (const float*)d_in[8];
    const float* W2   = (const float*)d_in[9];
    const float* b2   = (const float*)d_in[10];
    const float* ln2g = (const float*)d_in[11];
    const float* ln2b = (const float*)d_in[12];
    float* out = (float*)d_out;

    // ws layout (~5.7 MB)
    short* partKV = (short*)d_ws;                       // 512*4*1024 bf16
    float* partKs = (float*)(partKV + 2097152);         // 512*4*128  f32
    short* KVt    = (short*)(partKs + 262144);          // 64*1024    bf16 [m][d]
    float* Ksf    = (float*)(KVt + 65536);              // 64*32      f32
    short* Wqt    = (short*)(Ksf + 2048);
    short* Wkt    = Wqt + 16384;
    short* Wvt    = Wkt + 16384;
    short* Wot    = Wvt + 16384;
    short* W1t    = Wot + 16384;                        // [512][128]
    short* W2t    = W1t + 65536;                        // [128][512]

    kw_conv<<<768, 256, 0, stream>>>(Wq, Wk, Wv, Wo, W1, W2, Wqt, Wkt, Wvt, Wot, W1t, W2t);
    k1_kv<<<512, 256, 0, stream>>>(x, Wkt, Wvt, partKV, partKs);
    k2_red<<<64, 256, 0, stream>>>(partKV, partKs, KVt, Ksf);
    k3_main<<<512, 512, 0, stream>>>(x, Wqt, Wot, KVt, Ksf, ln1g, ln1b, W1t, b1,
                                     W2t, b2, ln2g, ln2b, out);
}